// Round 1
// baseline (4561.581 us; speedup 1.0000x reference)
//
#include <hip/hip_runtime.h>
#include <math.h>

#define E_EDGES 100000

// ---------------- structs passed by value as kernargs ----------------
struct CsrArgs { int nslots; int relid[18]; int nd[18]; int cntoff[18]; int rpoff[18]; };

struct ConvArgs {
  const float* xsrc[6];
  const int*   rowptr[6];
  const int*   esrc[6];
  const float* wl[6];
  const float* xdst;
  const float* wrsum;
  const float* blsum;
  float*       out;
  int nrels;
  int nd;
};

struct WsumArgs { int nrels[5]; int relid[5][6]; };

// ---------------- generic fp32 GEMM: C = op(A[M,K] @ W[K,N] + b) ----------------
// grid: (ceil(M/64), N/128), block 256. Thread: 8 rows x 4 cols.
__global__ __launch_bounds__(256) void gemm_kernel(
    const float* __restrict__ A, const float* __restrict__ W,
    const float* __restrict__ bias, float* __restrict__ C,
    int M, int K, int N, int relu)
{
  __shared__ float sA[64][36];   // [row][k], pitch 36 breaks bank conflicts on stage
  const int tid = threadIdx.x;
  const int tx = tid & 31, ty = tid >> 5;
  const int rowbase = blockIdx.x * 64;
  const int colbase = blockIdx.y * 128;
  float acc[8][4];
  #pragma unroll
  for (int i = 0; i < 8; i++)
    #pragma unroll
    for (int j = 0; j < 4; j++) acc[i][j] = 0.f;

  for (int k0 = 0; k0 < K; k0 += 32) {
    #pragma unroll
    for (int i = 0; i < 8; i++) {
      int flat = tid + i * 256;
      int kk = flat & 31, r = flat >> 5;
      int gr = rowbase + r, gk = k0 + kk;
      sA[r][kk] = (gr < M && gk < K) ? A[(long)gr * K + gk] : 0.f;
    }
    __syncthreads();
    #pragma unroll 8
    for (int kk = 0; kk < 32; kk++) {
      float4 wv = make_float4(0.f, 0.f, 0.f, 0.f);
      if (k0 + kk < K) wv = *(const float4*)&W[(long)(k0 + kk) * N + colbase + tx * 4];
      #pragma unroll
      for (int i = 0; i < 8; i++) {
        float av = sA[ty * 8 + i][kk];
        acc[i][0] += av * wv.x; acc[i][1] += av * wv.y;
        acc[i][2] += av * wv.z; acc[i][3] += av * wv.w;
      }
    }
    __syncthreads();
  }
  float4 bv = make_float4(0.f, 0.f, 0.f, 0.f);
  if (bias) bv = *(const float4*)&bias[colbase + tx * 4];
  #pragma unroll
  for (int i = 0; i < 8; i++) {
    int gr = rowbase + ty * 8 + i;
    if (gr < M) {
      float4 o;
      o.x = acc[i][0] + bv.x; o.y = acc[i][1] + bv.y;
      o.z = acc[i][2] + bv.z; o.w = acc[i][3] + bv.w;
      if (relu) { o.x = fmaxf(o.x, 0.f); o.y = fmaxf(o.y, 0.f); o.z = fmaxf(o.z, 0.f); o.w = fmaxf(o.w, 0.f); }
      *(float4*)&C[(long)gr * N + colbase + tx * 4] = o;
    }
  }
}

// ---------------- CSR build ----------------
__global__ __launch_bounds__(256) void hist_kernel(const int* __restrict__ edges,
                                                   int* __restrict__ cnt, CsrArgs a)
{
  int slot = blockIdx.y;
  int e = blockIdx.x * 256 + threadIdx.x;
  if (e >= E_EDGES) return;
  int r = a.relid[slot];
  int dst = edges[(r * 2 + 1) * E_EDGES + e];
  atomicAdd(&cnt[a.cntoff[slot] + dst], 1);
}

__global__ __launch_bounds__(256) void scan_kernel(const int* __restrict__ cnt,
                                                   int* __restrict__ rowptr, CsrArgs a)
{
  __shared__ int sbuf[256];
  int slot = blockIdx.x;
  int n = a.nd[slot], cb = a.cntoff[slot], rb = a.rpoff[slot];
  int tid = threadIdx.x;
  int carry = 0;
  for (int c0 = 0; c0 < n; c0 += 256) {
    int i = c0 + tid;
    int v = (i < n) ? cnt[cb + i] : 0;
    sbuf[tid] = v;
    __syncthreads();
    #pragma unroll
    for (int off = 1; off < 256; off <<= 1) {
      int t = (tid >= off) ? sbuf[tid - off] : 0;
      __syncthreads();
      sbuf[tid] += t;
      __syncthreads();
    }
    if (i < n) rowptr[rb + i] = carry + sbuf[tid] - v;
    carry += sbuf[255];
    __syncthreads();
  }
  if (tid == 0) rowptr[rb + n] = carry;
}

__global__ __launch_bounds__(256) void scatter_kernel(const int* __restrict__ edges,
                                                      int* __restrict__ cursor,
                                                      int* __restrict__ esrc, CsrArgs a)
{
  int slot = blockIdx.y;
  int e = blockIdx.x * 256 + threadIdx.x;
  if (e >= E_EDGES) return;
  int r = a.relid[slot];
  int src = edges[r * 2 * E_EDGES + e];
  int dst = edges[(r * 2 + 1) * E_EDGES + e];
  int pos = atomicAdd(&cursor[a.rpoff[slot] + dst], 1);
  esrc[slot * E_EDGES + pos] = src;
}

// ---------------- wr / bl sums per dst-type group ----------------
__global__ __launch_bounds__(256) void wrsum_kernel(const float* __restrict__ wr,
                                                    const float* __restrict__ bl,
                                                    float* __restrict__ wrsum,
                                                    float* __restrict__ blsum, WsumArgs a)
{
  int g = blockIdx.x >> 6;
  int chunk = blockIdx.x & 63;
  int idx = chunk * 256 + threadIdx.x;  // 0..16383
  float s = 0.f;
  for (int i = 0; i < a.nrels[g]; i++) s += wr[(long)a.relid[g][i] * 16384 + idx];
  wrsum[(long)g * 16384 + idx] = s;
  if (chunk == 0 && threadIdx.x < 128) {
    float b = 0.f;
    for (int i = 0; i < a.nrels[g]; i++) b += bl[a.relid[g][i] * 128 + threadIdx.x];
    blsum[g * 128 + threadIdx.x] = b;
  }
}

// ---------------- fused hetero-conv for one dst type ----------------
// per 64-row tile: loop relations {aggregate mean -> LDS; acc += mean @ wl[r]},
// then acc += xdst @ wrsum; out = acc + sum(bl).
__global__ __launch_bounds__(256) void conv_kernel(ConvArgs a)
{
  __shared__ float sm[64 * 128];
  const int tid = threadIdx.x;
  const int tx = tid & 31, ty = tid >> 5;
  const int rowbase = blockIdx.x * 64;
  const int frow = tid >> 7;        // 0..1
  const int feat = tid & 127;
  float acc[8][4];
  #pragma unroll
  for (int i = 0; i < 8; i++)
    #pragma unroll
    for (int j = 0; j < 4; j++) acc[i][j] = 0.f;

  for (int rel = 0; rel <= a.nrels; rel++) {
    if (rel < a.nrels) {
      const int* rp = a.rowptr[rel];
      const int* es = a.esrc[rel];
      const float* xs = a.xsrc[rel];
      for (int it = 0; it < 32; it++) {
        int r = rowbase + it * 2 + frow;
        float s = 0.f;
        if (r < a.nd) {
          int c0 = rp[r], c1 = rp[r + 1];
          for (int e = c0; e < c1; e++) {
            int srcn = es[e];
            s += xs[(long)srcn * 128 + feat];
          }
          int c = c1 - c0; if (c < 1) c = 1;
          s *= 1.0f / (float)c;
        }
        sm[(it * 2 + frow) * 128 + feat] = s;
      }
    } else {
      const float* xd = a.xdst;
      for (int it = 0; it < 32; it++) {
        int r = rowbase + it * 2 + frow;
        sm[(it * 2 + frow) * 128 + feat] = (r < a.nd) ? xd[(long)r * 128 + feat] : 0.f;
      }
    }
    __syncthreads();
    const float* w = (rel < a.nrels) ? a.wl[rel] : a.wrsum;
    for (int k = 0; k < 128; k += 4) {
      float4 w0 = *(const float4*)&w[(k + 0) * 128 + tx * 4];
      float4 w1 = *(const float4*)&w[(k + 1) * 128 + tx * 4];
      float4 w2 = *(const float4*)&w[(k + 2) * 128 + tx * 4];
      float4 w3 = *(const float4*)&w[(k + 3) * 128 + tx * 4];
      #pragma unroll
      for (int i = 0; i < 8; i++) {
        float4 av = *(const float4*)&sm[(ty * 8 + i) * 128 + k];
        acc[i][0] += av.x * w0.x + av.y * w1.x + av.z * w2.x + av.w * w3.x;
        acc[i][1] += av.x * w0.y + av.y * w1.y + av.z * w2.y + av.w * w3.y;
        acc[i][2] += av.x * w0.z + av.y * w1.z + av.z * w2.z + av.w * w3.z;
        acc[i][3] += av.x * w0.w + av.y * w1.w + av.z * w2.w + av.w * w3.w;
      }
    }
    __syncthreads();
  }
  float4 bv = *(const float4*)&a.blsum[tx * 4];
  #pragma unroll
  for (int i = 0; i < 8; i++) {
    int gr = rowbase + ty * 8 + i;
    if (gr < a.nd) {
      float4 o;
      o.x = acc[i][0] + bv.x; o.y = acc[i][1] + bv.y;
      o.z = acc[i][2] + bv.z; o.w = acc[i][3] + bv.w;
      *(float4*)&a.out[(long)gr * 128 + tx * 4] = o;
    }
  }
}

// ---------------- cross-layer ID-matched scatter (binary search) ----------------
__global__ __launch_bounds__(128) void xscatter_kernel(const int* __restrict__ map0,
                                                       const int* __restrict__ map1,
                                                       const float* __restrict__ src,
                                                       float* __restrict__ dst, int n)
{
  __shared__ int spos;
  int j = blockIdx.x;
  if (threadIdx.x == 0) {
    int key = map1[j];
    int lo = 0, hi = n - 1, pos = -1;
    while (lo <= hi) {
      int mid = (lo + hi) >> 1;
      int v = map0[mid];
      if (v == key) { pos = mid; break; }
      if (v < key) lo = mid + 1; else hi = mid - 1;
    }
    spos = pos;
  }
  __syncthreads();
  int p = spos;
  if (p >= 0) dst[(long)j * 128 + threadIdx.x] = src[(long)p * 128 + threadIdx.x];
}

// ---------------- head: out[row*2+col] = post(hid[row,:256] . w2 + b2) ----------------
__global__ __launch_bounds__(64) void head_reduce_kernel(const float* __restrict__ hid,
                                                         const float* __restrict__ w2,
                                                         const float* __restrict__ b2,
                                                         float* __restrict__ out,
                                                         int col, int dosig)
{
  int row = blockIdx.x;
  int lane = threadIdx.x;
  const float* h = hid + (long)row * 256;
  float s = h[lane] * w2[lane] + h[lane + 64] * w2[lane + 64]
          + h[lane + 128] * w2[lane + 128] + h[lane + 192] * w2[lane + 192];
  #pragma unroll
  for (int off = 32; off >= 1; off >>= 1) s += __shfl_down(s, off, 64);
  if (lane == 0) {
    float v = s + b2[0];
    if (dosig) v = 1.0f / (1.0f + expf(-v));
    out[row * 2 + col] = v;
  }
}

// ---------------- host orchestration ----------------
extern "C" void kernel_launch(void* const* d_in, const int* in_sizes, int n_in,
                              void* d_out, int out_size, void* d_ws, size_t ws_size,
                              hipStream_t stream)
{
  static const int NT[6] = {25000, 15000, 4000, 12000, 12000, 15000};
  static const int REL_S[19] = {2,0,2,1,0,1,3,3,1,3,1,3,4,5,0,5,1,0,1};
  static const int REL_D[19] = {0,2,1,2,1,0,3,1,3,1,3,4,3,0,5,1,5,1,0};

  auto xin   = [&](int t, int L) { return (const float*)d_in[L * 13 + 2 * t]; };
  auto mapin = [&](int t, int L) { return (const int*)d_in[L * 13 + 2 * t + 1]; };
  const int* edges0 = (const int*)d_in[12];
  const int* edges1 = (const int*)d_in[25];
  const float* W_in_atac  = (const float*)d_in[26];
  const float* b_in_atac  = (const float*)d_in[27];
  const float* W_in_gene  = (const float*)d_in[28];
  const float* b_in_gene  = (const float*)d_in[29];
  const float* W_in_pname = (const float*)d_in[30];
  const float* b_in_pname = (const float*)d_in[31];
  const float* conv_wl = (const float*)d_in[32];
  const float* conv_bl = (const float*)d_in[33];
  const float* conv_wr = (const float*)d_in[34];
  const float* mlp_w1 = (const float*)d_in[35];
  const float* mlp_b1 = (const float*)d_in[36];
  const float* mlp_w2 = (const float*)d_in[37];
  const float* mlp_b2 = (const float*)d_in[38];
  const float* gd_w1 = (const float*)d_in[39];
  const float* gd_b1 = (const float*)d_in[40];
  const float* gd_w2 = (const float*)d_in[41];
  const float* gd_b2 = (const float*)d_in[42];
  const float* gv_w1 = (const float*)d_in[43];
  const float* gv_b1 = (const float*)d_in[44];
  const float* gv_w2 = (const float*)d_in[45];
  const float* gv_b2 = (const float*)d_in[46];
  float* out = (float*)d_out;

  // ---- workspace carve (floats then ints), ~144 MB ----
  float* p = (float*)d_ws;
  auto take = [&](size_t n) { float* q = p; p += n; return q; };
  float* X0a  = take((size_t)25000 * 128);
  float* X0g  = take((size_t)15000 * 128);
  float* X0p  = take((size_t)12000 * 128);
  float* X1a  = take((size_t)25000 * 128);
  float* X1g  = take((size_t)15000 * 128);
  float* X1t  = take((size_t)4000 * 128);
  float* X1pr = take((size_t)12000 * 128);
  float* X1e  = take((size_t)15000 * 128);
  float* NW[6];
  NW[0] = take((size_t)25000 * 128);
  NW[1] = take((size_t)15000 * 128);
  NW[2] = take((size_t)4000 * 128);
  NW[3] = take((size_t)12000 * 128);
  NW[4] = nullptr;                       // (3,4) relation is dead code downstream
  NW[5] = take((size_t)15000 * 128);
  float* G1  = take((size_t)15000 * 128);
  float* HID = take((size_t)25000 * 256);
  float* WRS = take((size_t)5 * 16384);
  float* BLS = take((size_t)5 * 128);
  int* ip = (int*)p;
  auto takei = [&](size_t n) { int* q = ip; ip += n; return q; };
  int* CNT  = takei(276000);
  int* RP   = takei(276018);
  int* CUR  = takei(276018);
  int* ESRC = takei((size_t)18 * E_EDGES);

  const float* X0ptr[6] = {X0a, X0g, xin(2,0), xin(3,0), X0p, xin(5,0)};
  float*       X1ptr[6] = {X1a, X1g, X1t, X1pr, nullptr, X1e};

  // dst-type groups (layer-0 relation lists; gene's list identical in layer 1)
  static const int GD[5]       = {0, 1, 2, 3, 5};
  static const int GNR[5]      = {4, 6, 2, 4, 2};
  static const int GRELS[5][6] = {{0,5,13,18,0,0},{2,4,7,9,15,17},{1,3,0,0,0,0},
                                  {6,8,10,12,0,0},{14,16,0,0,0,0}};

  // 1) wr/bl sums per group
  WsumArgs wa;
  for (int g = 0; g < 5; g++) {
    wa.nrels[g] = GNR[g];
    for (int i = 0; i < 6; i++) wa.relid[g][i] = GRELS[g][i];
  }
  hipLaunchKernelGGL(wrsum_kernel, dim3(320), dim3(256), 0, stream,
                     conv_wr, conv_bl, WRS, BLS, wa);

  auto gemm = [&](const float* A, const float* W, const float* b, float* C,
                  int M, int K, int N, int relu) {
    hipLaunchKernelGGL(gemm_kernel, dim3((M + 63) / 64, N / 128), dim3(256), 0, stream,
                       A, W, b, C, M, K, N, relu);
  };

  // 2) input linears (pname1 is dead code) + passthrough copies for layer-1
  gemm(xin(0,0), W_in_atac,  b_in_atac,  X0a, 25000, 257, 128, 0);
  gemm(xin(1,0), W_in_gene,  b_in_gene,  X0g, 15000, 129, 128, 0);
  gemm(xin(4,0), W_in_pname, b_in_pname, X0p, 12000, 129, 128, 0);
  gemm(xin(0,1), W_in_atac,  b_in_atac,  X1a, 25000, 257, 128, 0);
  gemm(xin(1,1), W_in_gene,  b_in_gene,  X1g, 15000, 129, 128, 0);
  hipMemcpyAsync(X1t,  xin(2,1), (size_t)4000  * 128 * 4, hipMemcpyDeviceToDevice, stream);
  hipMemcpyAsync(X1pr, xin(3,1), (size_t)12000 * 128 * 4, hipMemcpyDeviceToDevice, stream);
  hipMemcpyAsync(X1e,  xin(5,1), (size_t)15000 * 128 * 4, hipMemcpyDeviceToDevice, stream);

  // 3) CSR layer 0 (18 live relations)
  static const int L0R[18] = {0,1,2,3,4,5,6,7,8,9,10,12,13,14,15,16,17,18};
  int rpoffByRel[19], slotByRel[19];
  CsrArgs c0; c0.nslots = 18;
  {
    int co = 0, ro = 0;
    for (int s = 0; s < 18; s++) {
      int r = L0R[s];
      c0.relid[s] = r; int nd = NT[REL_D[r]];
      c0.nd[s] = nd; c0.cntoff[s] = co; c0.rpoff[s] = ro;
      rpoffByRel[r] = ro; slotByRel[r] = s;
      co += nd; ro += nd + 1;
    }
    hipMemsetAsync(CNT, 0, (size_t)co * 4, stream);
    hipLaunchKernelGGL(hist_kernel, dim3(391, 18), dim3(256), 0, stream, edges0, CNT, c0);
    hipLaunchKernelGGL(scan_kernel, dim3(18), dim3(256), 0, stream, CNT, RP, c0);
    hipMemcpyAsync(CUR, RP, (size_t)ro * 4, hipMemcpyDeviceToDevice, stream);
    hipLaunchKernelGGL(scatter_kernel, dim3(391, 18), dim3(256), 0, stream, edges0, CUR, ESRC, c0);
  }

  // 4) fused conv layer 0, one launch per dst type
  for (int g = 0; g < 5; g++) {
    int d = GD[g];
    ConvArgs ca{};
    ca.nrels = GNR[g]; ca.nd = NT[d];
    for (int i = 0; i < GNR[g]; i++) {
      int r = GRELS[g][i];
      ca.xsrc[i]   = X0ptr[REL_S[r]];
      ca.rowptr[i] = RP + rpoffByRel[r];
      ca.esrc[i]   = ESRC + (long)slotByRel[r] * E_EDGES;
      ca.wl[i]     = conv_wl + (long)r * 16384;
    }
    ca.xdst = X0ptr[d]; ca.wrsum = WRS + (long)g * 16384; ca.blsum = BLS + g * 128;
    ca.out = NW[d];
    hipLaunchKernelGGL(conv_kernel, dim3((NT[d] + 63) / 64), dim3(256), 0, stream, ca);
  }

  // 5) per-type MLP (in-place on NW[d]) + cross-layer scatter into X1
  for (int g = 0; g < 5; g++) {
    int d = GD[g];
    gemm(NW[d], mlp_w1 + (long)d * 128 * 256, mlp_b1 + d * 256, HID, NT[d], 128, 256, 1);
    gemm(HID,   mlp_w2 + (long)d * 256 * 128, mlp_b2 + d * 128, NW[d], NT[d], 256, 128, 0);
    hipLaunchKernelGGL(xscatter_kernel, dim3(NT[d]), dim3(128), 0, stream,
                       mapin(d,0), mapin(d,1), NW[d], X1ptr[d], NT[d]);
  }

  // 6) CSR layer 1 (only the 6 gene-dst relations matter)
  static const int L1R[6] = {2, 4, 7, 9, 15, 17};
  int rpoff1[19], slot1[19];
  CsrArgs c1; c1.nslots = 6;
  {
    int co = 0, ro = 0;
    for (int s = 0; s < 6; s++) {
      int r = L1R[s];
      c1.relid[s] = r; c1.nd[s] = 15000; c1.cntoff[s] = co; c1.rpoff[s] = ro;
      rpoff1[r] = ro; slot1[r] = s;
      co += 15000; ro += 15001;
    }
    hipMemsetAsync(CNT, 0, (size_t)co * 4, stream);
    hipLaunchKernelGGL(hist_kernel, dim3(391, 6), dim3(256), 0, stream, edges1, CNT, c1);
    hipLaunchKernelGGL(scan_kernel, dim3(6), dim3(256), 0, stream, CNT, RP, c1);
    hipMemcpyAsync(CUR, RP, (size_t)ro * 4, hipMemcpyDeviceToDevice, stream);
    hipLaunchKernelGGL(scatter_kernel, dim3(391, 6), dim3(256), 0, stream, edges1, CUR, ESRC, c1);
  }

  // 7) fused conv layer 1, gene only
  {
    ConvArgs ca{};
    ca.nrels = 6; ca.nd = 15000;
    for (int i = 0; i < 6; i++) {
      int r = L1R[i];
      ca.xsrc[i]   = X1ptr[REL_S[r]];
      ca.rowptr[i] = RP + rpoff1[r];
      ca.esrc[i]   = ESRC + (long)slot1[r] * E_EDGES;
      ca.wl[i]     = conv_wl + (long)r * 16384;
    }
    ca.xdst = X1g; ca.wrsum = WRS + 1 * 16384; ca.blsum = BLS + 1 * 128; ca.out = G1;
    hipLaunchKernelGGL(conv_kernel, dim3((15000 + 63) / 64), dim3(256), 0, stream, ca);
  }

  // 8) gene heads
  gemm(G1, gd_w1, gd_b1, HID, 15000, 128, 256, 1);
  hipLaunchKernelGGL(head_reduce_kernel, dim3(15000), dim3(64), 0, stream,
                     HID, gd_w2, gd_b2, out, 0, 1);
  gemm(G1, gv_w1, gv_b1, HID, 15000, 128, 256, 1);
  hipLaunchKernelGGL(head_reduce_kernel, dim3(15000), dim3(64), 0, stream,
                     HID, gv_w2, gv_b2, out, 1, 0);
}